// Round 10
// baseline (93.011 us; speedup 1.0000x reference)
//
#include <hip/hip_runtime.h>
#include <stdint.h>

// Tropical (max-plus) matmul: Y[b][j] = max_k X[b][k] + W[j][k]
// M=512, N=1024, K=1024, fp32 in/out. (max,+) -> no MFMA, VALU only.
//
// R10: W-stationary-in-registers design. Prepass packs W -> Wt[kp][j]
// (f16 k-pairs, j-contiguous). Each wave: 64 j's (j=lane), one 128-k slice,
// W column slice loaded ONCE into 64 VGPRs; k-loop reads only broadcast
// X words from LDS (staged once per block, one barrier) and issues
// v_pk_add_f16/v_pk_max_f16 into 4 independent acc chains. S=8 split-K
// partials in d_ws + max-combine.

typedef _Float16 h1;
typedef _Float16 __attribute__((ext_vector_type(2))) h2;
typedef __fp16 __attribute__((ext_vector_type(2))) fp16x2;  // cvt_pkrtz return

#define M_DIM 512
#define N_DIM 1024
#define K_DIM 1024
#define BG 16     // b's per block
#define KPW 64    // k-pairs per slice (=128 k) -> W regs per wave
#define NSL 8     // k slices

#define NEGP 0xFBFFFBFFu  // packed (-65504, -65504)

__device__ __forceinline__ uint32_t pk_add(uint32_t a, uint32_t b) {
    uint32_t d;
    asm("v_pk_add_f16 %0, %1, %2" : "=v"(d) : "v"(a), "v"(b));
    return d;
}
__device__ __forceinline__ uint32_t pk_max(uint32_t a, uint32_t b) {
    uint32_t d;
    asm("v_pk_max_f16 %0, %1, %2" : "=v"(d) : "v"(a), "v"(b));
    return d;
}
__device__ __forceinline__ uint32_t pkrtz(float a, float b) {
    fp16x2 p = __builtin_amdgcn_cvt_pkrtz(a, b);
    return __builtin_bit_cast(uint32_t, p);
}

// ---- pass 1: Wt[kp][j] (uint32 = packed f16 pair (k,k+1)) <- W[j][k] fp32 ----
__global__ __launch_bounds__(256)
void pack_w(const float* __restrict__ W, uint32_t* __restrict__ Wt) {
    __shared__ uint32_t Lt[64][36];  // [j][kp]; stride 36 words, 16B-aligned

    const int tid = threadIdx.x;
    const int k0 = blockIdx.x * 64;   // 16 k-tiles
    const int j0 = blockIdx.y * 64;   // 16 j-tiles

    {   // load: j-row r, 16 k's/thread -> 8 packed kp words
        const int r  = tid >> 2;
        const int cg = (tid & 3) * 16;
        const float* g = &W[(size_t)(j0 + r) * K_DIM + k0 + cg];
        float4 f0 = *(const float4*)(g + 0);
        float4 f1 = *(const float4*)(g + 4);
        float4 f2 = *(const float4*)(g + 8);
        float4 f3 = *(const float4*)(g + 12);
        uint4 a = {pkrtz(f0.x, f0.y), pkrtz(f0.z, f0.w), pkrtz(f1.x, f1.y), pkrtz(f1.z, f1.w)};
        uint4 b = {pkrtz(f2.x, f2.y), pkrtz(f2.z, f2.w), pkrtz(f3.x, f3.y), pkrtz(f3.z, f3.w)};
        *(uint4*)&Lt[r][(tid & 3) * 8 + 0] = a;
        *(uint4*)&Lt[r][(tid & 3) * 8 + 4] = b;
    }
    __syncthreads();
    {   // write: kp row, 8 j's/thread
        const int kp = tid >> 3;            // 0..31
        const int jg = (tid & 7) * 8;
        uint32_t w[8];
#pragma unroll
        for (int i = 0; i < 8; i++) w[i] = Lt[jg + i][kp];
        uint32_t* o = Wt + (size_t)(k0 / 2 + kp) * N_DIM + j0 + jg;
        *(uint4*)(o + 0) = *(uint4*)&w[0];
        *(uint4*)(o + 4) = *(uint4*)&w[4];
    }
}

// ---- pass 2: W-stationary mm ----
__global__ __launch_bounds__(256, 4)
void tropical_mm_wreg(const float* __restrict__ X, const uint32_t* __restrict__ Wt,
                      float* __restrict__ out) {
    __shared__ uint32_t Xs[BG][KPW];   // 4 KB: 16 b x 64 kp, broadcast-read

    const int tid  = threadIdx.x;
    const int lane = tid & 63;
    const int wv   = tid >> 6;
    const int j    = blockIdx.x * 256 + wv * 64 + lane;  // this thread's column
    const int bb   = blockIdx.y * BG;                    // 32 b-groups
    const int sb   = blockIdx.z;                         // 8 slices
    const int k0p  = sb * KPW;

    // W column slice -> registers (64 coalesced 256B loads, L2-resident)
    uint32_t wreg[KPW];
    {
        const uint32_t* wp = Wt + (size_t)k0p * N_DIM + j;
#pragma unroll
        for (int kp = 0; kp < KPW; kp++) wreg[kp] = wp[(size_t)kp * N_DIM];
    }

    // stage X tile: 16 b x 64 kp (8 floats -> 1 uint4 per thread)
    {
        const int b  = tid >> 4;          // 0..15
        const int kq = (tid & 15) * 4;    // kp offset
        const float* g = &X[(size_t)(bb + b) * K_DIM + (size_t)(k0p + kq) * 2];
        float4 f0 = *(const float4*)g;
        float4 f1 = *(const float4*)(g + 4);
        uint4 v = {pkrtz(f0.x, f0.y), pkrtz(f0.z, f0.w),
                   pkrtz(f1.x, f1.y), pkrtz(f1.z, f1.w)};
        *(uint4*)&Xs[b][kq] = v;
    }
    __syncthreads();

    float* dst = out + (size_t)sb * M_DIM * N_DIM;
#pragma unroll 2
    for (int b = 0; b < BG; b++) {
        uint32_t a0 = NEGP, a1 = NEGP, a2 = NEGP, a3 = NEGP;
#pragma unroll
        for (int g = 0; g < KPW / 4; g++) {
            uint4 xv = *(const uint4*)&Xs[b][g * 4];   // broadcast ds_read_b128
            a0 = pk_max(a0, pk_add(wreg[4 * g + 0], xv.x));
            a1 = pk_max(a1, pk_add(wreg[4 * g + 1], xv.y));
            a2 = pk_max(a2, pk_add(wreg[4 * g + 2], xv.z));
            a3 = pk_max(a3, pk_add(wreg[4 * g + 3], xv.w));
        }
        uint32_t m = pk_max(pk_max(a0, a1), pk_max(a2, a3));
        h2 v = __builtin_bit_cast(h2, m);
        dst[(size_t)(bb + b) * N_DIM + j] = fmaxf((float)v[0], (float)v[1]);
    }
}

// ---- pass 3: merge slices ----
__global__ __launch_bounds__(256)
void combine_max_kernel(const float* __restrict__ part, float* __restrict__ out, int S) {
    const int idx = blockIdx.x * blockDim.x + threadIdx.x;  // over float4s
    const size_t stride = (size_t)M_DIM * N_DIM;
    float4 a = ((const float4*)part)[idx];
    for (int s = 1; s < S; s++) {
        float4 b = ((const float4*)(part + (size_t)s * stride))[idx];
        a.x = fmaxf(a.x, b.x);
        a.y = fmaxf(a.y, b.y);
        a.z = fmaxf(a.z, b.z);
        a.w = fmaxf(a.w, b.w);
    }
    ((float4*)out)[idx] = a;
}

extern "C" void kernel_launch(void* const* d_in, const int* in_sizes, int n_in,
                              void* d_out, int out_size, void* d_ws, size_t ws_size,
                              hipStream_t stream) {
    const float* X = (const float*)d_in[0];   // [512][1024]
    const float* W = (const float*)d_in[1];   // [1024][1024]
    float* out = (float*)d_out;               // [512][1024]

    const size_t wt_bytes = (size_t)(K_DIM / 2) * N_DIM * sizeof(uint32_t);  // 2 MB
    uint32_t* Wt = (uint32_t*)d_ws;
    float* part = (float*)((char*)d_ws + wt_bytes);   // NSL x 2 MB partials

    pack_w<<<dim3(K_DIM / 64, N_DIM / 64), 256, 0, stream>>>(W, Wt);

    dim3 grid(N_DIM / 256, M_DIM / BG, NSL);  // 4 x 32 x 8 = 1024 blocks
    tropical_mm_wreg<<<grid, 256, 0, stream>>>(X, Wt, part);

    const int n4 = M_DIM * N_DIM / 4;  // 131072 float4
    combine_max_kernel<<<n4 / 256, 256, 0, stream>>>(part, out, NSL);
}

// Round 11
// 82.726 us; speedup vs baseline: 1.1243x; 1.1243x over previous
//
#include <hip/hip_runtime.h>
#include <stdint.h>

// Tropical (max-plus) matmul: Y[b][j] = max_k X[b][k] + W[j][k]
// M=512, N=1024, K=1024, fp32 in/out.
//
// R11: EXACT candidate pruning. W = randn*0.02 => per-row spread
// D_j = maxW_j - minW_j <= D ~ 0.13, while X's top-gap ~ 0.3. Theorem:
// k with X[b,k] <= Xmax_b - D can never be argmax for any j (loses to
// k* = argmax X[b,:] because W[j,k]-W[j,k*] <= D_j <= D). So
// Y[b,j] = max_{k in C_b}(X[b,k]+W[j,k]), C_b = {k: X[b,k] > Xmax_b - D},
// |C_b| ~ 1-3. Compute shrinks ~300x; everything in exact fp32.
// CAP=64 slots; overflow (prob ~0) falls back to full k-loop => always exact.
//
// Pipeline (all tiny, memory-bound):
//   memset D=0
//   K1 reduce:   rows of W -> spread -> atomicMax D; rows of X -> Xmax[b]
//   K2 transpose: Wt[k][j] fp32 (so candidate k-rows are j-contiguous)
//   K3 candidates: C_b lists + counts
//   K4 emit:     Y[b][j] = max over C_b (X[b,k] + Wt[k][j]) (float4)

#define M_DIM 512
#define N_DIM 1024
#define K_DIM 1024
#define CAP 64

// d_ws layout
#define OFF_D     0            // 4 B   (uint bits of D, atomicMax)
#define OFF_XMAX  1024         // 512 floats
#define OFF_CNT   (16*1024)    // 512 ints
#define OFF_IDX   (32*1024)    // 512*CAP ints (128 KB)
#define OFF_WT    (1024*1024)  // 1024*1024 floats (4 MB)

__global__ __launch_bounds__(256)
void reduce_rows(const float* __restrict__ X, const float* __restrict__ W,
                 float* __restrict__ Xmax, unsigned int* __restrict__ Dbits) {
    __shared__ float s1[256];
    __shared__ float s2[256];
    const int tid = threadIdx.x;
    const int bid = blockIdx.x;

    if (bid < N_DIM) {
        // W row j: compute max-min spread, atomicMax into D
        const float4 v = ((const float4*)W)[bid * (K_DIM / 4) + tid];
        float mx = fmaxf(fmaxf(v.x, v.y), fmaxf(v.z, v.w));
        float mn = fminf(fminf(v.x, v.y), fminf(v.z, v.w));
        s1[tid] = mx; s2[tid] = mn;
        __syncthreads();
        for (int s = 128; s > 0; s >>= 1) {
            if (tid < s) {
                s1[tid] = fmaxf(s1[tid], s1[tid + s]);
                s2[tid] = fminf(s2[tid], s2[tid + s]);
            }
            __syncthreads();
        }
        if (tid == 0) {
            float d = s1[0] - s2[0];           // > 0
            atomicMax(Dbits, __float_as_uint(d));
        }
    } else {
        // X row b: row max
        const int b = bid - N_DIM;
        const float4 v = ((const float4*)X)[b * (K_DIM / 4) + tid];
        s1[tid] = fmaxf(fmaxf(v.x, v.y), fmaxf(v.z, v.w));
        __syncthreads();
        for (int s = 128; s > 0; s >>= 1) {
            if (tid < s) s1[tid] = fmaxf(s1[tid], s1[tid + s]);
            __syncthreads();
        }
        if (tid == 0) Xmax[b] = s1[0];
    }
}

__global__ __launch_bounds__(256)
void transpose_w(const float* __restrict__ W, float* __restrict__ Wt) {
    __shared__ float L[64][65];   // +1 pad: column reads conflict-free
    const int tid = threadIdx.x;
    const int k0 = blockIdx.x * 64;
    const int j0 = blockIdx.y * 64;

    {   // load 64 j x 64 k: thread reads 4 float4 (16 k) of one j-row
        const int r = tid >> 2;          // j-local 0..63
        const int q = tid & 3;           // 16-k group
        const float* g = &W[(size_t)(j0 + r) * K_DIM + k0 + q * 16];
#pragma unroll
        for (int t = 0; t < 4; t++) {
            float4 f = *(const float4*)(g + 4 * t);
            L[r][q * 16 + 4 * t + 0] = f.x;
            L[r][q * 16 + 4 * t + 1] = f.y;
            L[r][q * 16 + 4 * t + 2] = f.z;
            L[r][q * 16 + 4 * t + 3] = f.w;
        }
    }
    __syncthreads();
    {   // write 64 k x 64 j: thread writes 16 j's of one k-row (4 float4)
        const int kk = tid >> 2;         // k-local 0..63
        const int q  = tid & 3;          // 16-j group
        float* o = &Wt[(size_t)(k0 + kk) * N_DIM + j0 + q * 16];
#pragma unroll
        for (int t = 0; t < 4; t++) {
            float4 f = {L[q * 16 + 4 * t + 0][kk], L[q * 16 + 4 * t + 1][kk],
                        L[q * 16 + 4 * t + 2][kk], L[q * 16 + 4 * t + 3][kk]};
            *(float4*)(o + 4 * t) = f;
        }
    }
}

__global__ __launch_bounds__(256)
void build_cands(const float* __restrict__ X, const float* __restrict__ Xmax,
                 const unsigned int* __restrict__ Dbits,
                 int* __restrict__ cnt, int* __restrict__ idx) {
    __shared__ int scnt;
    __shared__ int sidx[CAP];
    const int tid = threadIdx.x;
    const int b = blockIdx.x;
    if (tid == 0) scnt = 0;
    __syncthreads();

    const float D = __uint_as_float(*Dbits) * 1.0001f + 1e-6f;  // pad vs fp rounding
    const float thr = Xmax[b] - D;
    const float4 v = ((const float4*)X)[b * (K_DIM / 4) + tid];
    const float vv[4] = {v.x, v.y, v.z, v.w};
#pragma unroll
    for (int c = 0; c < 4; c++) {
        if (vv[c] > thr) {
            int p = atomicAdd(&scnt, 1);
            if (p < CAP) sidx[p] = tid * 4 + c;
        }
    }
    __syncthreads();
    if (tid == 0) cnt[b] = scnt;           // uncapped (overflow detect)
    if (tid < CAP && tid < scnt) idx[b * CAP + tid] = sidx[tid];
}

__global__ __launch_bounds__(256)
void emit_y(const float* __restrict__ X, const float* __restrict__ Wt,
            const int* __restrict__ cnt, const int* __restrict__ idx,
            float* __restrict__ out) {
    const int tid = threadIdx.x;
    const int b = blockIdx.x;
    const int n = cnt[b];

    float4 acc = {-3.0e38f, -3.0e38f, -3.0e38f, -3.0e38f};
    if (n <= CAP) {
        for (int c = 0; c < n; c++) {
            const int k = idx[b * CAP + c];
            const float xv = X[(size_t)b * K_DIM + k];
            const float4 w = ((const float4*)Wt)[k * (N_DIM / 4) + tid];
            acc.x = fmaxf(acc.x, xv + w.x);
            acc.y = fmaxf(acc.y, xv + w.y);
            acc.z = fmaxf(acc.z, xv + w.z);
            acc.w = fmaxf(acc.w, xv + w.w);
        }
    } else {
        // overflow fallback: full exact scan (probability ~0, correctness anchor)
        for (int k = 0; k < K_DIM; k++) {
            const float xv = X[(size_t)b * K_DIM + k];
            const float4 w = ((const float4*)Wt)[k * (N_DIM / 4) + tid];
            acc.x = fmaxf(acc.x, xv + w.x);
            acc.y = fmaxf(acc.y, xv + w.y);
            acc.z = fmaxf(acc.z, xv + w.z);
            acc.w = fmaxf(acc.w, xv + w.w);
        }
    }
    ((float4*)out)[b * (N_DIM / 4) + tid] = acc;
}

extern "C" void kernel_launch(void* const* d_in, const int* in_sizes, int n_in,
                              void* d_out, int out_size, void* d_ws, size_t ws_size,
                              hipStream_t stream) {
    const float* X = (const float*)d_in[0];   // [512][1024]
    const float* W = (const float*)d_in[1];   // [1024][1024]
    float* out = (float*)d_out;               // [512][1024]

    char* ws = (char*)d_ws;
    unsigned int* Dbits = (unsigned int*)(ws + OFF_D);
    float* Xmax = (float*)(ws + OFF_XMAX);
    int* cnt    = (int*)(ws + OFF_CNT);
    int* idx    = (int*)(ws + OFF_IDX);
    float* Wt   = (float*)(ws + OFF_WT);

    hipMemsetAsync(Dbits, 0, sizeof(unsigned int), stream);

    reduce_rows<<<N_DIM + M_DIM, 256, 0, stream>>>(X, W, Xmax, Dbits);
    transpose_w<<<dim3(K_DIM / 64, N_DIM / 64), 256, 0, stream>>>(W, Wt);
    build_cands<<<M_DIM, 256, 0, stream>>>(X, Xmax, Dbits, cnt, idx);
    emit_y<<<M_DIM, 256, 0, stream>>>(X, Wt, cnt, idx, out);
}

// Round 12
// 72.252 us; speedup vs baseline: 1.2873x; 1.1450x over previous
//
#include <hip/hip_runtime.h>
#include <stdint.h>

// Tropical (max-plus) matmul: Y[b][j] = max_k X[b][k] + W[j][k]
// M=512, N=1024, K=1024, fp32 in/out.
//
// R12: exact candidate pruning (R11 theorem) in TWO dispatches.
//   Theorem: with D >= max_j (max_k W[j,k] - min_k W[j,k]), any k with
//   X[b,k] <= Xmax_b - D loses to k* = argmax X[b,:] for EVERY j. So
//   Y[b,j] = max over C_b = {k : X[b,k] > Xmax_b - D}; |C_b| ~ 1-3 here
//   (W = randn*0.02 -> D ~ 0.15). Exact fp32; CAP overflow -> full-scan
//   fallback preserves exactness unconditionally.
// K1: spread[j] = max-min of W row j  (1024 blocks; plain stores to ws)
// K2: per b-row: D = max spread (4KB L2 read) -> Xmax -> candidates ->
//     emit from W columns (uncoalesced, L2-warm) -> coalesced float4 out.
// No memset / transpose / combine: dispatch overhead was ~38us of R11's time.

#define M_DIM 512
#define N_DIM 1024
#define K_DIM 1024
#define CAP 128

__global__ __launch_bounds__(256)
void w_spread(const float* __restrict__ W, float* __restrict__ spread) {
    __shared__ float smx[256];
    __shared__ float smn[256];
    const int tid = threadIdx.x;
    const int j = blockIdx.x;
    float4 v = ((const float4*)W)[j * (K_DIM / 4) + tid];
    smx[tid] = fmaxf(fmaxf(v.x, v.y), fmaxf(v.z, v.w));
    smn[tid] = fminf(fminf(v.x, v.y), fminf(v.z, v.w));
    __syncthreads();
    for (int s = 128; s > 0; s >>= 1) {
        if (tid < s) {
            smx[tid] = fmaxf(smx[tid], smx[tid + s]);
            smn[tid] = fminf(smn[tid], smn[tid + s]);
        }
        __syncthreads();
    }
    if (tid == 0) spread[j] = smx[0] - smn[0];
}

__global__ __launch_bounds__(256)
void emit_pruned(const float* __restrict__ X, const float* __restrict__ W,
                 const float* __restrict__ spread, float* __restrict__ out) {
    __shared__ float red[256];
    __shared__ float sval[CAP];
    __shared__ int sidx[CAP];
    __shared__ int scnt;

    const int tid = threadIdx.x;
    const int b = blockIdx.x;

    // --- D = max_j spread[j]  (1024 floats, L2) ---
    {
        float4 sp = ((const float4*)spread)[tid];
        red[tid] = fmaxf(fmaxf(sp.x, sp.y), fmaxf(sp.z, sp.w));
    }
    if (tid == 0) scnt = 0;
    __syncthreads();
    for (int s = 128; s > 0; s >>= 1) {
        if (tid < s) red[tid] = fmaxf(red[tid], red[tid + s]);
        __syncthreads();
    }
    const float D = red[0] * 1.0001f + 1e-6f;  // pad vs fp rounding of the bound
    __syncthreads();                            // before red[] reuse

    // --- Xmax_b ---
    const float4 xv = ((const float4*)X)[b * (K_DIM / 4) + tid];
    red[tid] = fmaxf(fmaxf(xv.x, xv.y), fmaxf(xv.z, xv.w));
    __syncthreads();
    for (int s = 128; s > 0; s >>= 1) {
        if (tid < s) red[tid] = fmaxf(red[tid], red[tid + s]);
        __syncthreads();
    }
    const float thr = red[0] - D;

    // --- candidate list ---
    const float xa[4] = {xv.x, xv.y, xv.z, xv.w};
#pragma unroll
    for (int c = 0; c < 4; c++) {
        if (xa[c] > thr) {
            int p = atomicAdd(&scnt, 1);
            if (p < CAP) { sidx[p] = tid * 4 + c; sval[p] = xa[c]; }
        }
    }
    __syncthreads();
    const int n = scnt;

    // --- emit: 4 j's per thread (j = 4*tid+q), coalesced float4 store ---
    float4 acc = {-3.0e38f, -3.0e38f, -3.0e38f, -3.0e38f};
    float* accp = (float*)&acc;
    if (n <= CAP) {
        for (int c = 0; c < n; c++) {
            const int k = sidx[c];
            const float xk = sval[c];
            const float* wc = W + k;  // column k: W[j*K_DIM + k]
#pragma unroll
            for (int q = 0; q < 4; q++) {
                const float w = wc[(size_t)(tid * 4 + q) * K_DIM];
                accp[q] = fmaxf(accp[q], xk + w);
            }
        }
    } else {
        // overflow fallback (prob ~0): exact full scan
        for (int k = 0; k < K_DIM; k++) {
            const float xk = X[(size_t)b * K_DIM + k];
            const float* wc = W + k;
#pragma unroll
            for (int q = 0; q < 4; q++) {
                const float w = wc[(size_t)(tid * 4 + q) * K_DIM];
                accp[q] = fmaxf(accp[q], xk + w);
            }
        }
    }
    ((float4*)out)[b * (N_DIM / 4) + tid] = acc;
}

extern "C" void kernel_launch(void* const* d_in, const int* in_sizes, int n_in,
                              void* d_out, int out_size, void* d_ws, size_t ws_size,
                              hipStream_t stream) {
    const float* X = (const float*)d_in[0];   // [512][1024]
    const float* W = (const float*)d_in[1];   // [1024][1024]
    float* out = (float*)d_out;               // [512][1024]
    float* spread = (float*)d_ws;             // 1024 floats (overwritten each call)

    w_spread<<<N_DIM, 256, 0, stream>>>(W, spread);
    emit_pruned<<<M_DIM, 256, 0, stream>>>(X, W, spread, out);
}

// Round 13
// 66.690 us; speedup vs baseline: 1.3947x; 1.0834x over previous
//
#include <hip/hip_runtime.h>
#include <stdint.h>

// Tropical (max-plus) matmul: Y[b][j] = max_k X[b][k] + W[j][k]
// M=512, N=1024, K=1024, fp32 in/out.
//
// Exact candidate pruning (R11 theorem): with D >= max_j spread_j,
// spread_j = max_k W[j,k] - min_k W[j,k], any k with X[b,k] <= Xmax_b - D
// loses to k* = argmax X[b,:] for every j. |C_b| ~ 1-3 (W = randn*0.02).
// Exact fp32; CAP overflow -> coalesced full scan fallback.
//
// R12 post-mortem: emit's column gather (4B used per 128B line, 4KB stride)
// cost ~27us. R13: K1 fuses W transpose (Wt[k][j]) + per-j tile min/max
// partials; K2 reduces partials -> D, builds candidates, emits from Wt ROWS
// (coalesced float4). Still 2 dispatches (dispatch overhead ~2.6us each).

#define M_DIM 512
#define N_DIM 1024
#define K_DIM 1024
#define CAP 128

// ws layout: Wt 4MB | pmax 64KB | pmin 64KB
#define OFF_WT    0
#define OFF_PMAX  (4u * 1024u * 1024u)
#define OFF_PMIN  (OFF_PMAX + 64u * 1024u)

// ---- K1: transpose 64x64 tile + per-j partial min/max over the tile ----
__global__ __launch_bounds__(256)
void transpose_spread(const float* __restrict__ W, float* __restrict__ Wt,
                      float* __restrict__ pmax, float* __restrict__ pmin) {
    __shared__ float L[64][65];     // +1 pad: column reads conflict-free
    __shared__ float smx[4][64];
    __shared__ float smn[4][64];

    const int tid = threadIdx.x;
    const int kt = blockIdx.x;      // k-tile 0..15
    const int jt = blockIdx.y;      // j-tile 0..15
    const int k0 = kt * 64, j0 = jt * 64;

    {   // load: j-row r, 16 k's per thread
        const int r = tid >> 2, q = tid & 3;
        const float* g = &W[(size_t)(j0 + r) * K_DIM + k0 + q * 16];
#pragma unroll
        for (int t = 0; t < 4; t++) {
            float4 f = *(const float4*)(g + 4 * t);
            L[r][q * 16 + 4 * t + 0] = f.x;
            L[r][q * 16 + 4 * t + 1] = f.y;
            L[r][q * 16 + 4 * t + 2] = f.z;
            L[r][q * 16 + 4 * t + 3] = f.w;
        }
    }
    __syncthreads();

    {   // write Wt tile: k-row kk, 16 j's per thread
        const int kk = tid >> 2, q = tid & 3;
        float* o = &Wt[(size_t)(k0 + kk) * N_DIM + j0 + q * 16];
#pragma unroll
        for (int t = 0; t < 4; t++) {
            float4 f = {L[q * 16 + 4 * t + 0][kk], L[q * 16 + 4 * t + 1][kk],
                        L[q * 16 + 4 * t + 2][kk], L[q * 16 + 4 * t + 3][kk]};
            *(float4*)(o + 4 * t) = f;
        }
    }

    {   // per-j partial min/max over this tile's 64 k's (4 threads/j)
        const int jl = tid & 63, seg = tid >> 6;
        float mx = -3.0e38f, mn = 3.0e38f;
#pragma unroll
        for (int i = 0; i < 16; i++) {
            float v = L[jl][seg * 16 + i];   // stride 65 words: conflict-free
            mx = fmaxf(mx, v);
            mn = fminf(mn, v);
        }
        smx[seg][jl] = mx;
        smn[seg][jl] = mn;
    }
    __syncthreads();
    if (tid < 64) {
        float mx = fmaxf(fmaxf(smx[0][tid], smx[1][tid]), fmaxf(smx[2][tid], smx[3][tid]));
        float mn = fminf(fminf(smn[0][tid], smn[1][tid]), fminf(smn[2][tid], smn[3][tid]));
        pmax[kt * N_DIM + j0 + tid] = mx;   // kt-major: K2 reduce is coalesced
        pmin[kt * N_DIM + j0 + tid] = mn;
    }
}

// ---- K2: D-reduce, Xmax, candidates, coalesced emit from Wt rows ----
__global__ __launch_bounds__(256)
void emit_pruned(const float* __restrict__ X, const float* __restrict__ Wt,
                 const float* __restrict__ pmax, const float* __restrict__ pmin,
                 float* __restrict__ out) {
    __shared__ float red[256];
    __shared__ float sval[CAP];
    __shared__ int sidx[CAP];
    __shared__ int scnt;

    const int tid = threadIdx.x;
    const int b = blockIdx.x;

    // --- D = max_j (max_kt pmax - min_kt pmin), coalesced float4 loads ---
    {
        float4 mx = {-3.0e38f, -3.0e38f, -3.0e38f, -3.0e38f};
        float4 mn = {3.0e38f, 3.0e38f, 3.0e38f, 3.0e38f};
#pragma unroll
        for (int kt = 0; kt < 16; kt++) {
            float4 a = ((const float4*)pmax)[kt * 256 + tid];
            float4 i = ((const float4*)pmin)[kt * 256 + tid];
            mx.x = fmaxf(mx.x, a.x); mx.y = fmaxf(mx.y, a.y);
            mx.z = fmaxf(mx.z, a.z); mx.w = fmaxf(mx.w, a.w);
            mn.x = fminf(mn.x, i.x); mn.y = fminf(mn.y, i.y);
            mn.z = fminf(mn.z, i.z); mn.w = fminf(mn.w, i.w);
        }
        float s0 = fmaxf(mx.x - mn.x, mx.y - mn.y);
        float s1 = fmaxf(mx.z - mn.z, mx.w - mn.w);
        red[tid] = fmaxf(s0, s1);
    }
    if (tid == 0) scnt = 0;
    __syncthreads();
    for (int s = 128; s > 0; s >>= 1) {
        if (tid < s) red[tid] = fmaxf(red[tid], red[tid + s]);
        __syncthreads();
    }
    const float D = red[0] * 1.0001f + 1e-6f;  // pad vs fp rounding of the bound
    __syncthreads();                            // before red[] reuse

    // --- Xmax_b ---
    const float4 xv = ((const float4*)X)[b * (K_DIM / 4) + tid];
    red[tid] = fmaxf(fmaxf(xv.x, xv.y), fmaxf(xv.z, xv.w));
    __syncthreads();
    for (int s = 128; s > 0; s >>= 1) {
        if (tid < s) red[tid] = fmaxf(red[tid], red[tid + s]);
        __syncthreads();
    }
    const float thr = red[0] - D;

    // --- candidate list ---
    const float xa[4] = {xv.x, xv.y, xv.z, xv.w};
#pragma unroll
    for (int c = 0; c < 4; c++) {
        if (xa[c] > thr) {
            int p = atomicAdd(&scnt, 1);
            if (p < CAP) { sidx[p] = tid * 4 + c; sval[p] = xa[c]; }
        }
    }
    __syncthreads();
    const int n = scnt;

    // --- emit: coalesced float4 reads of Wt rows ---
    float4 acc = {-3.0e38f, -3.0e38f, -3.0e38f, -3.0e38f};
    if (n <= CAP) {
        for (int c = 0; c < n; c++) {
            const int k = sidx[c];
            const float xk = sval[c];
            const float4 w = ((const float4*)Wt)[k * (N_DIM / 4) + tid];
            acc.x = fmaxf(acc.x, xk + w.x);
            acc.y = fmaxf(acc.y, xk + w.y);
            acc.z = fmaxf(acc.z, xk + w.z);
            acc.w = fmaxf(acc.w, xk + w.w);
        }
    } else {
        // overflow fallback (prob ~0): exact full scan, still coalesced
        for (int k = 0; k < K_DIM; k++) {
            const float xk = X[(size_t)b * K_DIM + k];
            const float4 w = ((const float4*)Wt)[k * (N_DIM / 4) + tid];
            acc.x = fmaxf(acc.x, xk + w.x);
            acc.y = fmaxf(acc.y, xk + w.y);
            acc.z = fmaxf(acc.z, xk + w.z);
            acc.w = fmaxf(acc.w, xk + w.w);
        }
    }
    ((float4*)out)[b * (N_DIM / 4) + tid] = acc;
}

extern "C" void kernel_launch(void* const* d_in, const int* in_sizes, int n_in,
                              void* d_out, int out_size, void* d_ws, size_t ws_size,
                              hipStream_t stream) {
    const float* X = (const float*)d_in[0];   // [512][1024]
    const float* W = (const float*)d_in[1];   // [1024][1024]
    float* out = (float*)d_out;               // [512][1024]

    char* ws = (char*)d_ws;
    float* Wt   = (float*)(ws + OFF_WT);
    float* pmax = (float*)(ws + OFF_PMAX);
    float* pmin = (float*)(ws + OFF_PMIN);

    transpose_spread<<<dim3(K_DIM / 64, N_DIM / 64), 256, 0, stream>>>(W, Wt, pmax, pmin);
    emit_pruned<<<M_DIM, 256, 0, stream>>>(X, Wt, pmax, pmin, out);
}